// Round 3
// baseline (372.904 us; speedup 1.0000x reference)
//
#include <hip/hip_runtime.h>
#include <stdint.h>

#define B_  32
#define D_  192
#define TX_ 256
#define TY_ 1024
#define NEGV -1e9f
// -0.5*log(2*pi)*D, computed in double, cast to f32 (matches reference const)
#define LPCONST ((float)(-176.43619837529715))

// ---------------- K0: row/col squared-norm terms -------------------------
__global__ __launch_bounds__(256) void k0_sq(const float* __restrict__ x,
                                             const float* __restrict__ y,
                                             float* __restrict__ xsq,
                                             float* __restrict__ ysq) {
    int gid = blockIdx.x * 256 + threadIdx.x;
    if (gid < B_ * TX_) {
        int b = gid >> 8, t = gid & 255;
        const float* p = x + (size_t)b * D_ * TX_ + t;
        float s = 0.f;
        #pragma unroll 8
        for (int d = 0; d < D_; ++d) { float v = p[(size_t)d * TX_]; s += v * v; }
        xsq[gid] = -0.5f * s;
    } else {
        int g = gid - B_ * TX_;
        int b = g >> 10, t = g & 1023;
        const float* p = y + (size_t)b * D_ * TY_ + t;
        float s = 0.f;
        #pragma unroll 8
        for (int d = 0; d < D_; ++d) { float v = p[(size_t)d * TY_]; s += v * v; }
        ysq[g] = -0.5f * s;
    }
}

// ---------------- K1: log_prior GEMM ------------------------------------
#define BT 128
#define BS 128
#define BK 32
__global__ __launch_bounds__(256) void k1_gemm(const float* __restrict__ x,
                                               const float* __restrict__ y,
                                               const float* __restrict__ xsq,
                                               const float* __restrict__ ysq,
                                               float* __restrict__ lp) {
    __shared__ float xs[BK][BT];
    __shared__ float ys[BK][BS];
    const int id = blockIdx.x;            // 0..511
    const int r  = id & 7;
    const int g  = id >> 3;               // 0..63
    const int b  = r + 8 * (g >> 4);      // 0..31
    const int sub = g & 15;               // 16 tiles per batch
    const int t0 = (sub >> 3) * BT;       // 2 t-tiles
    const int s0 = (sub & 7) * BS;        // 8 s-tiles
    const int tid = threadIdx.x;
    const int ti = tid & 15;   // t-group (fast dim -> coalesced stores)
    const int si = tid >> 4;   // s-group

    float acc[8][8];
    #pragma unroll
    for (int i = 0; i < 8; ++i)
        #pragma unroll
        for (int j = 0; j < 8; ++j) acc[i][j] = 0.f;

    const float* xg = x + (size_t)b * D_ * TX_ + t0;
    const float* yg = y + (size_t)b * D_ * TY_ + s0;

    for (int k0 = 0; k0 < D_; k0 += BK) {
        #pragma unroll
        for (int i = 0; i < 4; ++i) {
            int f = tid + i * 256;           // 0..1023 float4 slots
            int row = f >> 5;                // 0..31
            int col = (f & 31) * 4;          // 0..124
            float4 v = *(const float4*)(xg + (size_t)(k0 + row) * TX_ + col);
            *(float4*)&xs[row][col] = v;
            float4 w = *(const float4*)(yg + (size_t)(k0 + row) * TY_ + col);
            *(float4*)&ys[row][col] = w;
        }
        __syncthreads();
        #pragma unroll
        for (int k = 0; k < BK; ++k) {
            float xr[8], yr[8];
            *(float4*)&xr[0] = *(float4*)&xs[k][ti * 8];
            *(float4*)&xr[4] = *(float4*)&xs[k][ti * 8 + 4];
            *(float4*)&yr[0] = *(float4*)&ys[k][si * 8];
            *(float4*)&yr[4] = *(float4*)&ys[k][si * 8 + 4];
            #pragma unroll
            for (int i = 0; i < 8; ++i)
                #pragma unroll
                for (int j = 0; j < 8; ++j) acc[i][j] += xr[i] * yr[j];
        }
        __syncthreads();
    }

    float xq[8], yq[8];
    *(float4*)&xq[0] = *(const float4*)(xsq + b * TX_ + t0 + ti * 8);
    *(float4*)&xq[4] = *(const float4*)(xsq + b * TX_ + t0 + ti * 8 + 4);
    *(float4*)&yq[0] = *(const float4*)(ysq + b * TY_ + s0 + si * 8);
    *(float4*)&yq[4] = *(const float4*)(ysq + b * TY_ + s0 + si * 8 + 4);

    #pragma unroll
    for (int js = 0; js < 8; ++js) {
        float* op = lp + (size_t)(b * TY_ + s0 + si * 8 + js) * TX_ + t0 + ti * 8;
        float o[8];
        #pragma unroll
        for (int it = 0; it < 8; ++it) {
            float v = yq[js] + acc[it][js];
            v = v + xq[it];
            o[it] = v + LPCONST;
        }
        *(float4*)op       = *(float4*)&o[0];
        *(float4*)(op + 4) = *(float4*)&o[4];
    }
}

// ---------------- K2: forward DP + backtrack ----------------------------
// One wave per batch. Lane l owns t = 4l..4l+3.
// Column data DMA'd global->LDS via global_load_lds, 56 columns ahead,
// guarded by counted s_waitcnt vmcnt(48) (exactly one DMA per column in
// program order; compiler cannot track DMA->LDS deps so the wait is ours).
// 8-deep ds_read_b128 register ring hides LDS latency.
#define DPD 56            // DMA issue-ahead depth
#define RSLOTS 64         // LDS ring slots (1KB each)

__device__ __forceinline__ void gload16(const float* gp, float* lp_) {
    __builtin_amdgcn_global_load_lds(
        (const __attribute__((address_space(1))) unsigned int*)(gp),
        (__attribute__((address_space(3))) unsigned int*)(lp_), 16, 0, 0);
}

__global__ __launch_bounds__(64, 1) void k2_dp(const float* __restrict__ lp,
                                               const int* __restrict__ xlens,
                                               const int* __restrict__ ylens,
                                               unsigned char* __restrict__ path) {
    __shared__ float ring[RSLOTS * 256];   // 64 KB column ring
    __shared__ unsigned int RB[TX_][33];   // 33.8 KB backpointer bits (padded)
    __shared__ unsigned int PTw[TY_ / 4];  // 1 KB path bytes as words
    unsigned char* PT = (unsigned char*)PTw;

    const int b = blockIdx.x;
    const int l = threadIdx.x;
    const int xlen = xlens[b];
    const int ylen = ylens[b];
    const int send = (ylen + 31) & ~31;    // >=512, multiple of 32
    const float* gl = lp + (size_t)b * TY_ * TX_ + l * 4;  // lane's col base
    const int tt0 = l * 4;

    // ---- prologue: issue DMAs for columns 0..DPD (57 loads) ----
    #pragma unroll 1
    for (int i = 0; i <= DPD; ++i) {
        int sc = i;                                   // all < TY_
        gload16(gl + (size_t)sc * TX_, &ring[(i & (RSLOTS - 1)) * 256]);
    }
    asm volatile("s_waitcnt vmcnt(48)" ::: "memory");
    __builtin_amdgcn_sched_barrier(0);

    float4 rr0, rr1, rr2, rr3, rr4, rr5, rr6, rr7;
    rr0 = *(float4*)&ring[0 * 256 + l * 4];
    rr1 = *(float4*)&ring[1 * 256 + l * 4];
    rr2 = *(float4*)&ring[2 * 256 + l * 4];
    rr3 = *(float4*)&ring[3 * 256 + l * 4];
    rr4 = *(float4*)&ring[4 * 256 + l * 4];
    rr5 = *(float4*)&ring[5 * 256 + l * 4];
    rr6 = *(float4*)&ring[6 * 256 + l * 4];
    rr7 = *(float4*)&ring[7 * 256 + l * 4];

    float p0, p1, p2, p3, shv;
    unsigned int rw0 = 0, rw1 = 0, rw2 = 0, rw3 = 0;

    // s = 0: col0 = where(t==0, lp, NEG)
    p0 = (l == 0) ? rr0.x : NEGV;
    p1 = NEGV; p2 = NEGV; p3 = NEGV;
    shv = NEGV;
    rr0 = *(float4*)&ring[8 * 256 + l * 4];   // col 8 -> rr0

// entry: p0..p3 = column (s-1) values; shv = shfl_up of p3 at column (s-1).
#define PROC(s, fv, PRE) {                                              \
    unsigned int sbit = 1u << ((s) & 31);                               \
    bool e0 = false, e1 = false, e2 = false, e3 = false;                \
    if (PRE) { e0 = (tt0 == (s));     e1 = (tt0 + 1 == (s));            \
               e2 = (tt0 + 2 == (s)); e3 = (tt0 + 3 == (s)); }          \
    if ((l != 0) && (e0 || (shv > p0))) rw0 |= sbit;                    \
    if (e1 || (p0 > p1)) rw1 |= sbit;                                   \
    if (e2 || (p1 > p2)) rw2 |= sbit;                                   \
    if (e3 || (p2 > p3)) rw3 |= sbit;                                   \
    float c3 = (fv).w + fmaxf(e3 ? NEGV : p3, p2);                      \
    float nsh = __shfl_up(c3, 1);                                       \
    float c2 = (fv).z + fmaxf(e2 ? NEGV : p2, p1);                      \
    float c1 = (fv).y + fmaxf(e1 ? NEGV : p1, p0);                      \
    float c0 = (fv).x + fmaxf(e0 ? NEGV : p0, (l == 0) ? NEGV : shv);   \
    p0 = c0; p1 = c1; p2 = c2; p3 = c3; shv = nsh;                      \
}

#define FLUSH(w) { RB[tt0][w] = rw0; RB[tt0 + 1][w] = rw1;              \
                   RB[tt0 + 2][w] = rw2; RB[tt0 + 3][w] = rw3;          \
                   rw0 = rw1 = rw2 = rw3 = 0; }

// per-column body: issue DMA(s+DPD), wait, ds_read col s+8 into rr, PROC s.
#define COLBODY(s, rr, PRE) {                                           \
    int sc = (s) + DPD; if (sc > TY_ - 1) sc = TY_ - 1;                 \
    gload16(gl + (size_t)sc * TX_,                                      \
            &ring[(((s) + DPD) & (RSLOTS - 1)) * 256]);                 \
    asm volatile("s_waitcnt vmcnt(48)" ::: "memory");                   \
    __builtin_amdgcn_sched_barrier(0);                                  \
    float4 nf = *(float4*)&ring[((((s) + 8) & (RSLOTS - 1)) * 256) + l * 4]; \
    PROC(s, rr, PRE)                                                    \
    rr = nf;                                                            \
}

    COLBODY(1, rr1, true)
    COLBODY(2, rr2, true)
    COLBODY(3, rr3, true)
    COLBODY(4, rr4, true)
    COLBODY(5, rr5, true)
    COLBODY(6, rr6, true)
    COLBODY(7, rr7, true)

    #pragma unroll 1
    for (int sb = 8; sb < 256; sb += 8) {
        COLBODY(sb + 0, rr0, true)
        COLBODY(sb + 1, rr1, true)
        COLBODY(sb + 2, rr2, true)
        COLBODY(sb + 3, rr3, true)
        COLBODY(sb + 4, rr4, true)
        COLBODY(sb + 5, rr5, true)
        COLBODY(sb + 6, rr6, true)
        COLBODY(sb + 7, rr7, true)
        if (((sb + 7) & 31) == 31) FLUSH((sb + 7) >> 5)
    }
    #pragma unroll 1
    for (int sb = 256; sb < send; sb += 8) {
        COLBODY(sb + 0, rr0, false)
        COLBODY(sb + 1, rr1, false)
        COLBODY(sb + 2, rr2, false)
        COLBODY(sb + 3, rr3, false)
        COLBODY(sb + 4, rr4, false)
        COLBODY(sb + 5, rr5, false)
        COLBODY(sb + 6, rr6, false)
        COLBODY(sb + 7, rr7, false)
        if (((sb + 7) & 31) == 31) FLUSH((sb + 7) >> 5)
    }
    __syncthreads();

    if (l == 0) {
        // run-length backtrack with speculative 'below' word prefetch.
        int idx = xlen - 1;
        int yi = ylen - 1;
        int w = yi >> 5;
        unsigned int cur = RB[idx][w];
        unsigned int below = (idx > 0) ? RB[idx - 1][w] : 0u;
        while (yi >= 0) {
            unsigned int m = cur & (0xFFFFFFFFu >> (31 - (yi & 31)));
            if (m) {
                int hb = 31 - __clz(m);
                int lo = (w << 5) + hb;           // move happens at col lo
                for (int q = lo; q <= yi; ++q) PT[q] = (unsigned char)idx;
                --idx;
                cur = below;
                below = (idx > 0) ? RB[idx - 1][w] : 0u;
                yi = lo - 1;
                if (yi >= 0 && (yi >> 5) < w) {
                    w = yi >> 5;
                    cur = RB[idx][w];
                    below = (idx > 0) ? RB[idx - 1][w] : 0u;
                }
            } else {
                int lo = w << 5;
                for (int q = lo; q <= yi; ++q) PT[q] = (unsigned char)idx;
                yi = lo - 1;
                if (yi >= 0) {
                    --w;
                    cur = RB[idx][w];
                    below = (idx > 0) ? RB[idx - 1][w] : 0u;
                }
            }
        }
    }
    __syncthreads();
    {
        unsigned int* pd = (unsigned int*)(path + b * TY_);
        #pragma unroll
        for (int k = 0; k < 4; ++k) pd[l + k * 64] = PTw[l + k * 64];
    }
}

// ---------------- K3: materialize one-hot output ------------------------
__global__ __launch_bounds__(256) void k3_out(const unsigned char* __restrict__ path,
                                              const int* __restrict__ ylens,
                                              float* __restrict__ out) {
    int F = blockIdx.x * 256 + threadIdx.x;       // float4 index, 2M total
    int yi = (F & 255) * 4;
    int t  = (F >> 8) & 255;
    int b  = F >> 16;
    int ylen = ylens[b];
    unsigned int pw = *(const unsigned int*)(path + b * TY_ + yi);
    float4 v;
    v.x = (((pw      ) & 255u) == (unsigned)t && yi     < ylen) ? 1.f : 0.f;
    v.y = (((pw >>  8) & 255u) == (unsigned)t && yi + 1 < ylen) ? 1.f : 0.f;
    v.z = (((pw >> 16) & 255u) == (unsigned)t && yi + 2 < ylen) ? 1.f : 0.f;
    v.w = (((pw >> 24) & 255u) == (unsigned)t && yi + 3 < ylen) ? 1.f : 0.f;
    ((float4*)out)[F] = v;
}

extern "C" void kernel_launch(void* const* d_in, const int* in_sizes, int n_in,
                              void* d_out, int out_size, void* d_ws, size_t ws_size,
                              hipStream_t stream) {
    const float* x  = (const float*)d_in[0];
    const int*   xl = (const int*)d_in[1];
    const float* y  = (const float*)d_in[2];
    const int*   yl = (const int*)d_in[3];
    float* out = (float*)d_out;

    char* ws = (char*)d_ws;
    float* xsq = (float*)ws;                           //  32 KB
    float* ysq = (float*)(ws + 32 * 1024);             // 128 KB
    unsigned char* path = (unsigned char*)(ws + 160 * 1024); // 32 KB

    // reuse d_out (exactly B*TY*TX floats = 32 MB) as log_prior scratch;
    // K3 fully overwrites it afterwards.
    float* lp = out;

    k0_sq  <<<160, 256, 0, stream>>>(x, y, xsq, ysq);
    k1_gemm<<<512, 256, 0, stream>>>(x, y, xsq, ysq, lp);
    k2_dp  <<<B_, 64, 0, stream>>>(lp, xl, yl, path);
    k3_out <<<(B_ * TX_ * TY_ / 4) / 256, 256, 0, stream>>>(path, yl, out);
}

// Round 4
// 185.289 us; speedup vs baseline: 2.0126x; 2.0126x over previous
//
#include <hip/hip_runtime.h>
#include <stdint.h>

#define B_  32
#define D_  192
#define TX_ 256
#define TY_ 1024
#define NEGV -1e9f
// -0.5*log(2*pi)*D, computed in double, cast to f32 (matches reference const)
#define LPCONST ((float)(-176.43619837529715))

// ---------------- K0: row/col squared-norm terms -------------------------
__global__ __launch_bounds__(256) void k0_sq(const float* __restrict__ x,
                                             const float* __restrict__ y,
                                             float* __restrict__ xsq,
                                             float* __restrict__ ysq) {
    int gid = blockIdx.x * 256 + threadIdx.x;
    if (gid < B_ * TX_) {
        int b = gid >> 8, t = gid & 255;
        const float* p = x + (size_t)b * D_ * TX_ + t;
        float s = 0.f;
        #pragma unroll 8
        for (int d = 0; d < D_; ++d) { float v = p[(size_t)d * TX_]; s += v * v; }
        xsq[gid] = -0.5f * s;
    } else {
        int g = gid - B_ * TX_;
        int b = g >> 10, t = g & 1023;
        const float* p = y + (size_t)b * D_ * TY_ + t;
        float s = 0.f;
        #pragma unroll 8
        for (int d = 0; d < D_; ++d) { float v = p[(size_t)d * TY_]; s += v * v; }
        ysq[g] = -0.5f * s;
    }
}

// ---------------- K1: log_prior GEMM ------------------------------------
#define BT 128
#define BS 128
#define BK 32
__global__ __launch_bounds__(256) void k1_gemm(const float* __restrict__ x,
                                               const float* __restrict__ y,
                                               const float* __restrict__ xsq,
                                               const float* __restrict__ ysq,
                                               float* __restrict__ lp) {
    __shared__ float xs[BK][BT];
    __shared__ float ys[BK][BS];
    const int id = blockIdx.x;            // 0..511
    const int r  = id & 7;
    const int g  = id >> 3;               // 0..63
    const int b  = r + 8 * (g >> 4);      // 0..31
    const int sub = g & 15;               // 16 tiles per batch
    const int t0 = (sub >> 3) * BT;       // 2 t-tiles
    const int s0 = (sub & 7) * BS;        // 8 s-tiles
    const int tid = threadIdx.x;
    const int ti = tid & 15;   // t-group (fast dim -> coalesced stores)
    const int si = tid >> 4;   // s-group

    float acc[8][8];
    #pragma unroll
    for (int i = 0; i < 8; ++i)
        #pragma unroll
        for (int j = 0; j < 8; ++j) acc[i][j] = 0.f;

    const float* xg = x + (size_t)b * D_ * TX_ + t0;
    const float* yg = y + (size_t)b * D_ * TY_ + s0;

    for (int k0 = 0; k0 < D_; k0 += BK) {
        #pragma unroll
        for (int i = 0; i < 4; ++i) {
            int f = tid + i * 256;           // 0..1023 float4 slots
            int row = f >> 5;                // 0..31
            int col = (f & 31) * 4;          // 0..124
            float4 v = *(const float4*)(xg + (size_t)(k0 + row) * TX_ + col);
            *(float4*)&xs[row][col] = v;
            float4 w = *(const float4*)(yg + (size_t)(k0 + row) * TY_ + col);
            *(float4*)&ys[row][col] = w;
        }
        __syncthreads();
        #pragma unroll
        for (int k = 0; k < BK; ++k) {
            float xr[8], yr[8];
            *(float4*)&xr[0] = *(float4*)&xs[k][ti * 8];
            *(float4*)&xr[4] = *(float4*)&xs[k][ti * 8 + 4];
            *(float4*)&yr[0] = *(float4*)&ys[k][si * 8];
            *(float4*)&yr[4] = *(float4*)&ys[k][si * 8 + 4];
            #pragma unroll
            for (int i = 0; i < 8; ++i)
                #pragma unroll
                for (int j = 0; j < 8; ++j) acc[i][j] += xr[i] * yr[j];
        }
        __syncthreads();
    }

    float xq[8], yq[8];
    *(float4*)&xq[0] = *(const float4*)(xsq + b * TX_ + t0 + ti * 8);
    *(float4*)&xq[4] = *(const float4*)(xsq + b * TX_ + t0 + ti * 8 + 4);
    *(float4*)&yq[0] = *(const float4*)(ysq + b * TY_ + s0 + si * 8);
    *(float4*)&yq[4] = *(const float4*)(ysq + b * TY_ + s0 + si * 8 + 4);

    #pragma unroll
    for (int js = 0; js < 8; ++js) {
        float* op = lp + (size_t)(b * TY_ + s0 + si * 8 + js) * TX_ + t0 + ti * 8;
        float o[8];
        #pragma unroll
        for (int it = 0; it < 8; ++it) {
            float v = yq[js] + acc[it][js];
            v = v + xq[it];
            o[it] = v + LPCONST;
        }
        *(float4*)op       = *(float4*)&o[0];
        *(float4*)(op + 4) = *(float4*)&o[4];
    }
}

// ---------------- K2: forward DP + backtrack ----------------------------
// One wave per batch. Lane l owns t = 4l..4l+3.
// 64-deep float4 VGPR prefetch ring (ring slot == unroll index, all static
// -> registers). Compiler inserts its own counted vmcnt before each use.
// Shuffle is issued off the critical chain (shfl of column s's c3 is
// consumed at column s+1's c0). Backpointer bits row-major in LDS;
// run-length backtrack via __clz; path staged in LDS, copied out wave-wide.
__global__ __launch_bounds__(64, 1) void k2_dp(const float* __restrict__ lp,
                                               const int* __restrict__ xlens,
                                               const int* __restrict__ ylens,
                                               unsigned char* __restrict__ path) {
    __shared__ unsigned int RB[TX_][33];   // padded stride
    __shared__ unsigned int PTw[TY_ / 4];  // path bytes staged as words
    unsigned char* PT = (unsigned char*)PTw;

    const int b = blockIdx.x;
    const int l = threadIdx.x;
    const int xlen = xlens[b];
    const int ylen = ylens[b];
    const float* base = lp + (size_t)b * TY_ * TX_ + l * 4;
    const int tt0 = l * 4;

#define LDCOL(s) (*(const float4*)(base + (size_t)(((s) < TY_) ? (s) : (TY_ - 1)) * TX_))

// entry: p0..p3 = column (s-1) values; shv = shfl_up of p3 at column (s-1).
// bits at column s compare column (s-1) values (reference backtrack predicate).
#define PROC(s, fv, PRE) {                                              \
    unsigned int sbit = 1u << ((s) & 31);                               \
    bool e0 = false, e1 = false, e2 = false, e3 = false;                \
    if (PRE) { e0 = (tt0 == (s));     e1 = (tt0 + 1 == (s));            \
               e2 = (tt0 + 2 == (s)); e3 = (tt0 + 3 == (s)); }          \
    if ((l != 0) && (e0 || (shv > p0))) rw0 |= sbit;                    \
    if (e1 || (p0 > p1)) rw1 |= sbit;                                   \
    if (e2 || (p1 > p2)) rw2 |= sbit;                                   \
    if (e3 || (p2 > p3)) rw3 |= sbit;                                   \
    float c3 = (fv).w + fmaxf(e3 ? NEGV : p3, p2);                      \
    float nsh = __shfl_up(c3, 1);                                       \
    float c2 = (fv).z + fmaxf(e2 ? NEGV : p2, p1);                      \
    float c1 = (fv).y + fmaxf(e1 ? NEGV : p1, p0);                      \
    float c0 = (fv).x + fmaxf(e0 ? NEGV : p0, (l == 0) ? NEGV : shv);   \
    p0 = c0; p1 = c1; p2 = c2; p3 = c3; shv = nsh;                      \
}

#define FLUSH(w) { RB[tt0][w] = rw0; RB[tt0 + 1][w] = rw1;              \
                   RB[tt0 + 2][w] = rw2; RB[tt0 + 3][w] = rw3;          \
                   rw0 = rw1 = rw2 = rw3 = 0; }

    float4 g[64];
    #pragma unroll
    for (int i = 0; i < 64; ++i) g[i] = LDCOL(i);

    float p0, p1, p2, p3, shv;
    unsigned int rw0 = 0, rw1 = 0, rw2 = 0, rw3 = 0;

    // s = 0: col0 = where(t==0, lp, NEG)
    p0 = (l == 0) ? g[0].x : NEGV;
    p1 = NEGV; p2 = NEGV; p3 = NEGV;
    shv = NEGV;                      // shfl of p3@col0 (all NEGV)
    g[0] = LDCOL(64);

    #pragma unroll
    for (int j = 1; j < 64; ++j) {
        PROC(j, g[j], true)
        g[j] = LDCOL(j + 64);
        if (j == 31 || j == 63) FLUSH(j >> 5)
    }
    #pragma unroll 1
    for (int sb = 64; sb < 256; sb += 64) {
        #pragma unroll
        for (int j = 0; j < 64; ++j) {
            PROC(sb + j, g[j], true)
            g[j] = LDCOL(sb + j + 64);
            if (j == 31 || j == 63) FLUSH((sb + j) >> 5)
        }
    }
    const int send64 = (ylen + 63) & ~63;   // >= 512, multiple of 64
    #pragma unroll 1
    for (int sb = 256; sb < send64; sb += 64) {
        #pragma unroll
        for (int j = 0; j < 64; ++j) {
            PROC(sb + j, g[j], false)
            g[j] = LDCOL(sb + j + 64);
            if (j == 31 || j == 63) FLUSH((sb + j) >> 5)
        }
    }
    __syncthreads();

    if (l == 0) {
        // run-length backtrack with speculative 'below' word prefetch.
        int idx = xlen - 1;
        int yi = ylen - 1;
        int w = yi >> 5;
        unsigned int cur = RB[idx][w];
        unsigned int below = (idx > 0) ? RB[idx - 1][w] : 0u;
        while (yi >= 0) {
            unsigned int m = cur & (0xFFFFFFFFu >> (31 - (yi & 31)));
            if (m) {
                int hb = 31 - __clz(m);
                int lo = (w << 5) + hb;           // move happens at col lo
                for (int q = lo; q <= yi; ++q) PT[q] = (unsigned char)idx;
                --idx;
                cur = below;
                below = (idx > 0) ? RB[idx - 1][w] : 0u;
                yi = lo - 1;
                if (yi >= 0 && (yi >> 5) < w) {
                    w = yi >> 5;
                    cur = RB[idx][w];
                    below = (idx > 0) ? RB[idx - 1][w] : 0u;
                }
            } else {
                int lo = w << 5;
                for (int q = lo; q <= yi; ++q) PT[q] = (unsigned char)idx;
                yi = lo - 1;
                if (yi >= 0) {
                    --w;
                    cur = RB[idx][w];
                    below = (idx > 0) ? RB[idx - 1][w] : 0u;
                }
            }
        }
    }
    __syncthreads();
    {
        unsigned int* pd = (unsigned int*)(path + b * TY_);
        #pragma unroll
        for (int k = 0; k < 4; ++k) pd[l + k * 64] = PTw[l + k * 64];
    }
}

// ---------------- K3: materialize one-hot output ------------------------
__global__ __launch_bounds__(256) void k3_out(const unsigned char* __restrict__ path,
                                              const int* __restrict__ ylens,
                                              float* __restrict__ out) {
    int F = blockIdx.x * 256 + threadIdx.x;       // float4 index, 2M total
    int yi = (F & 255) * 4;
    int t  = (F >> 8) & 255;
    int b  = F >> 16;
    int ylen = ylens[b];
    unsigned int pw = *(const unsigned int*)(path + b * TY_ + yi);
    float4 v;
    v.x = (((pw      ) & 255u) == (unsigned)t && yi     < ylen) ? 1.f : 0.f;
    v.y = (((pw >>  8) & 255u) == (unsigned)t && yi + 1 < ylen) ? 1.f : 0.f;
    v.z = (((pw >> 16) & 255u) == (unsigned)t && yi + 2 < ylen) ? 1.f : 0.f;
    v.w = (((pw >> 24) & 255u) == (unsigned)t && yi + 3 < ylen) ? 1.f : 0.f;
    ((float4*)out)[F] = v;
}

extern "C" void kernel_launch(void* const* d_in, const int* in_sizes, int n_in,
                              void* d_out, int out_size, void* d_ws, size_t ws_size,
                              hipStream_t stream) {
    const float* x  = (const float*)d_in[0];
    const int*   xl = (const int*)d_in[1];
    const float* y  = (const float*)d_in[2];
    const int*   yl = (const int*)d_in[3];
    float* out = (float*)d_out;

    char* ws = (char*)d_ws;
    float* xsq = (float*)ws;                           //  32 KB
    float* ysq = (float*)(ws + 32 * 1024);             // 128 KB
    unsigned char* path = (unsigned char*)(ws + 160 * 1024); // 32 KB

    // reuse d_out (exactly B*TY*TX floats = 32 MB) as log_prior scratch;
    // K3 fully overwrites it afterwards.
    float* lp = out;

    k0_sq  <<<160, 256, 0, stream>>>(x, y, xsq, ysq);
    k1_gemm<<<512, 256, 0, stream>>>(x, y, xsq, ysq, lp);
    k2_dp  <<<B_, 64, 0, stream>>>(lp, xl, yl, path);
    k3_out <<<(B_ * TX_ * TY_ / 4) / 256, 256, 0, stream>>>(path, yl, out);
}